// Round 4
// baseline (631.315 us; speedup 1.0000x reference)
//
#include <hip/hip_runtime.h>
#include <hip/hip_bf16.h>

#define NPOS 784
#define WDIM 28

__device__ __forceinline__ float wave_max64(float v) {
#pragma unroll
    for (int off = 32; off > 0; off >>= 1) v = fmaxf(v, __shfl_down(v, off, 64));
    return v;
}
__device__ __forceinline__ float wave_sum64(float v) {
#pragma unroll
    for (int off = 32; off > 0; off >>= 1) v += __shfl_down(v, off, 64);
    return v;
}

// Fully fused: qkv + embed tables + 4-rotation relative-position attention +
// output projection. ALL inputs are fp32 (per the reference: jnp.float32),
// output fp32. No d_ws usage. One block per (b, ij); loops over 8 heads;
// K/V tiles recomputed from x into a shared 50KB LDS buffer (K then V).
__global__ __launch_bounds__(256) void attn_all_kernel(
    const float* __restrict__ x,
    const float* __restrict__ wq, const float* __restrict__ bq,
    const float* __restrict__ wk, const float* __restrict__ bk,
    const float* __restrict__ wv, const float* __restrict__ bv,
    const float* __restrict__ w_out, const float* __restrict__ b_out,
    const float* __restrict__ rw1, const float* __restrict__ rb1,
    const float* __restrict__ rga, const float* __restrict__ rbe,
    const float* __restrict__ rw2, const float* __restrict__ rb2,
    const float* __restrict__ cw1, const float* __restrict__ cb1,
    const float* __restrict__ cga, const float* __restrict__ cbe,
    const float* __restrict__ cw2, const float* __restrict__ cb2,
    float* __restrict__ out)
{
    __shared__ float Er[110 * 8], Ec[110 * 8];   // embedding tables
    __shared__ float KV[16 * NPOS];              // K tile, then V tile (m-major)
    __shared__ float sc[4][NPOS];                // scores/probs, 4 rotations
    __shared__ float arow[110], acol[110];
    __shared__ float wred[4][4];
    __shared__ float Mg[4], invs[4];
    __shared__ float ovs[4][128];                // out_v[g][m*8+h]

    const int t    = threadIdx.x;
    const int b    = blockIdx.x / NPOS;
    const int ij   = blockIdx.x % NPOS;
    const int i    = ij / WDIM, j = ij % WDIM;
    const int lane = t & 63, wave = t >> 6;
    const float scale = 0.57735026918962576f;    // 1/sqrt(CIN=3)

    // ---- embedding-MLP tables (per block; trivial cost) ----
    {
        int d = -1;
        const float *w1 = rw1, *b1 = rb1, *ga = rga, *be = rbe, *w2 = rw2, *b2 = rb2;
        float* E = Er;
        if (t < 110) { d = t; }
        else if (t >= 128 && t < 238) { d = t - 128; w1 = cw1; b1 = cb1; ga = cga; be = cbe; w2 = cw2; b2 = cb2; E = Ec; }
        if (d >= 0) {
            float u = (d < 55) ? (-1.0f + (float)d * (2.0f / 54.0f))
                               : -(-1.0f + (float)(d - 55) * (2.0f / 54.0f));
            float hb[16], mu = 0.0f;
#pragma unroll
            for (int c = 0; c < 16; ++c) { hb[c] = u * w1[c] + b1[c]; mu += hb[c]; }
            mu *= (1.0f / 16.0f);
            float var = 0.0f;
#pragma unroll
            for (int c = 0; c < 16; ++c) { float dv = hb[c] - mu; var += dv * dv; }
            var *= (1.0f / 16.0f);
            float rstd = rsqrtf(var + 1e-5f);
#pragma unroll
            for (int c = 0; c < 16; ++c) {
                float hn = ga[c] * (hb[c] - mu) * rstd + be[c];
                hb[c] = hn / (1.0f + __expf(-hn));
            }
#pragma unroll
            for (int m = 0; m < 8; ++m) {
                float e = b2[m];
#pragma unroll
                for (int c = 0; c < 16; ++c) e += hb[c] * w2[m * 16 + c];
                E[d * 8 + m] = e;
            }
        }
    }

    // query-pixel x values (wave-uniform)
    const float xq0 = x[(b * 3 + 0) * NPOS + ij];
    const float xq1 = x[(b * 3 + 1) * NPOS + ij];
    const float xq2 = x[(b * 3 + 2) * NPOS + ij];

    for (int h = 0; h < 8; ++h) {
        __syncthreads();   // E ready (h=0); previous head's sc/KV/ovs reads done (h>0)

        // q in registers (uniform across threads)
        float q[16];
#pragma unroll
        for (int m = 0; m < 16; ++m) {
            int oc = m * 8 + h;
            q[m] = bq[oc] + wq[oc*3+0]*xq0 + wq[oc*3+1]*xq1 + wq[oc*3+2]*xq2;
        }

        // stage K tile (m-major: KV[m*784 + kl]); weights hoisted (wave-uniform)
        for (int kl = t; kl < NPOS; kl += 256) {
            float x0 = x[(b * 3 + 0) * NPOS + kl];
            float x1 = x[(b * 3 + 1) * NPOS + kl];
            float x2 = x[(b * 3 + 2) * NPOS + kl];
#pragma unroll
            for (int m = 0; m < 16; ++m) {
                int oc = m * 8 + h;
                KV[m * NPOS + kl] = bk[oc] + wk[oc*3+0]*x0 + wk[oc*3+1]*x1 + wk[oc*3+2]*x2;
            }
        }

        // positional row/col dot-products with q halves
        if (t < 110) {
            float a = 0.0f;
#pragma unroll
            for (int mm = 0; mm < 8; ++mm) a += q[mm] * Er[t * 8 + mm];
            arow[t] = a;
        } else if (t >= 128 && t < 238) {
            int d = t - 128;
            float a = 0.0f;
#pragma unroll
            for (int mm = 0; mm < 8; ++mm) a += q[8 + mm] * Ec[d * 8 + mm];
            acol[d] = a;
        }
        __syncthreads();   // K tile + arow/acol ready

        // fused content + 4-rotation scores + per-thread maxima
        float lm0 = -1e30f, lm1 = -1e30f, lm2 = -1e30f, lm3 = -1e30f;
        for (int kl = t; kl < NPOS; kl += 256) {
            float c = 0.0f;
#pragma unroll
            for (int m = 0; m < 16; ++m) c += q[m] * KV[m * NPOS + kl];
            int k  = kl / WDIM, l = kl - k * WDIM;
            int a  = k - i + 27;    // rel(i,k) in [0,54]
            int c2 = l - j + 27;    // rel(j,l) in [0,54]
            float s0 = (c + arow[a]      + acol[c2]     ) * scale;
            float s1 = (c + arow[c2+55]  + acol[a]      ) * scale;
            float s2 = (c + arow[a+55]   + acol[c2+55]  ) * scale;
            float s3 = (c + arow[c2]     + acol[a+55]   ) * scale;
            sc[0][kl] = s0; sc[1][kl] = s1; sc[2][kl] = s2; sc[3][kl] = s3;
            lm0 = fmaxf(lm0, s0); lm1 = fmaxf(lm1, s1);
            lm2 = fmaxf(lm2, s2); lm3 = fmaxf(lm3, s3);
        }
        lm0 = wave_max64(lm0); lm1 = wave_max64(lm1);
        lm2 = wave_max64(lm2); lm3 = wave_max64(lm3);
        if (lane == 0) { wred[0][wave]=lm0; wred[1][wave]=lm1; wred[2][wave]=lm2; wred[3][wave]=lm3; }
        __syncthreads();   // all score-loop KV reads complete after this
        if (t < 4) Mg[t] = fmaxf(fmaxf(wred[t][0], wred[t][1]), fmaxf(wred[t][2], wred[t][3]));
        __syncthreads();
        float M0 = Mg[0], M1 = Mg[1], M2 = Mg[2], M3 = Mg[3];

        // stage V tile (overwrites KV; safe: after the barrier above)
        for (int kl = t; kl < NPOS; kl += 256) {
            float x0 = x[(b * 3 + 0) * NPOS + kl];
            float x1 = x[(b * 3 + 1) * NPOS + kl];
            float x2 = x[(b * 3 + 2) * NPOS + kl];
#pragma unroll
            for (int m = 0; m < 16; ++m) {
                int oc = m * 8 + h;
                KV[m * NPOS + kl] = bv[oc] + wv[oc*3+0]*x0 + wv[oc*3+1]*x1 + wv[oc*3+2]*x2;
            }
        }

        // exp + per-thread sums
        float ls0 = 0.0f, ls1 = 0.0f, ls2 = 0.0f, ls3 = 0.0f;
        for (int kl = t; kl < NPOS; kl += 256) {
            float p0 = __expf(sc[0][kl] - M0); sc[0][kl] = p0; ls0 += p0;
            float p1 = __expf(sc[1][kl] - M1); sc[1][kl] = p1; ls1 += p1;
            float p2 = __expf(sc[2][kl] - M2); sc[2][kl] = p2; ls2 += p2;
            float p3 = __expf(sc[3][kl] - M3); sc[3][kl] = p3; ls3 += p3;
        }
        ls0 = wave_sum64(ls0); ls1 = wave_sum64(ls1);
        ls2 = wave_sum64(ls2); ls3 = wave_sum64(ls3);
        if (lane == 0) { wred[0][wave]=ls0; wred[1][wave]=ls1; wred[2][wave]=ls2; wred[3][wave]=ls3; }
        __syncthreads();   // V tile + sums ready
        if (t < 4) invs[t] = 1.0f / (wred[t][0] + wred[t][1] + wred[t][2] + wred[t][3]);
        __syncthreads();

        // PV: thread = (m = t>>4, ch = t&15); 49 kl per chunk; all 4 g at once.
        {
            int m = t >> 4, ch = t & 15;
            float a0 = 0.0f, a1 = 0.0f, a2 = 0.0f, a3 = 0.0f;
            int base = ch * 49;
            for (int s = 0; s < 49; ++s) {
                int kl = base + s;
                float vv = KV[m * NPOS + kl];
                a0 += sc[0][kl] * vv; a1 += sc[1][kl] * vv;
                a2 += sc[2][kl] * vv; a3 += sc[3][kl] * vv;
            }
#pragma unroll
            for (int off = 8; off > 0; off >>= 1) {
                a0 += __shfl_down(a0, off, 16); a1 += __shfl_down(a1, off, 16);
                a2 += __shfl_down(a2, off, 16); a3 += __shfl_down(a3, off, 16);
            }
            if (ch == 0) {
                ovs[0][m * 8 + h] = a0 * invs[0];
                ovs[1][m * 8 + h] = a1 * invs[1];
                ovs[2][m * 8 + h] = a2 * invs[2];
                ovs[3][m * 8 + h] = a3 * invs[3];
            }
        }
    }
    __syncthreads();

    // output projection: thread = (o = t>>2, g = t&3); out (B,64,G,28,28) fp32
    {
        int o = t >> 2, g = t & 3;
        float acc = b_out[o];
        const float* wr = w_out + o * 128;
        const float* ov = ovs[g];
#pragma unroll 8
        for (int c = 0; c < 128; ++c) acc += wr[c] * ov[c];
        out[((b * 64 + o) * 4 + g) * NPOS + ij] = acc;
    }
}

extern "C" void kernel_launch(void* const* d_in, const int* in_sizes, int n_in,
                              void* d_out, int out_size, void* d_ws, size_t ws_size,
                              hipStream_t stream)
{
    const float* x     = (const float*)d_in[0];
    const float* wq    = (const float*)d_in[1];
    const float* bq    = (const float*)d_in[2];
    const float* wk    = (const float*)d_in[3];
    const float* bk    = (const float*)d_in[4];
    const float* wv    = (const float*)d_in[5];
    const float* bv    = (const float*)d_in[6];
    const float* w_out = (const float*)d_in[7];
    const float* b_out = (const float*)d_in[8];
    const float* rw1 = (const float*)d_in[9];
    const float* rb1 = (const float*)d_in[10];
    const float* rga = (const float*)d_in[11];
    const float* rbe = (const float*)d_in[12];
    const float* rw2 = (const float*)d_in[13];
    const float* rb2 = (const float*)d_in[14];
    const float* cw1 = (const float*)d_in[15];
    const float* cb1 = (const float*)d_in[16];
    const float* cga = (const float*)d_in[17];
    const float* cbe = (const float*)d_in[18];
    const float* cw2 = (const float*)d_in[19];
    const float* cb2 = (const float*)d_in[20];
    // d_in[21]/d_in[22] (ridx/cidx, int32) unused: closed-form rotation indices.
    // d_ws deliberately unused.

    attn_all_kernel<<<4 * NPOS, 256, 0, stream>>>(
        x, wq, bq, wk, bk, wv, bv, w_out, b_out,
        rw1, rb1, rga, rbe, rw2, rb2,
        cw1, cb1, cga, cbe, cw2, cb2,
        (float*)d_out);
}

// Round 5
// 469.401 us; speedup vs baseline: 1.3449x; 1.3449x over previous
//
#include <hip/hip_runtime.h>
#include <hip/hip_bf16.h>

#define NPOS 784
#define WDIM 28

__device__ __forceinline__ float wave_max64(float v) {
#pragma unroll
    for (int off = 32; off > 0; off >>= 1) v = fmaxf(v, __shfl_down(v, off, 64));
    return v;
}
__device__ __forceinline__ float wave_sum64(float v) {
#pragma unroll
    for (int off = 32; off > 0; off >>= 1) v += __shfl_down(v, off, 64);
    return v;
}

// ---------------- kernel 1: fused 1x1-conv q/k/v -> d_ws ----------------
// All fp32. Layout [bh][kl][m], m contiguous (16 floats = 64 B per row).
__global__ __launch_bounds__(256) void qkv_kernel(
    const float* __restrict__ x,
    const float* __restrict__ wq, const float* __restrict__ bq,
    const float* __restrict__ wk, const float* __restrict__ bk,
    const float* __restrict__ wv, const float* __restrict__ bv,
    float* __restrict__ Q, float* __restrict__ K, float* __restrict__ V)
{
    int idx = blockIdx.x * 256 + threadIdx.x;
    if (idx >= 4 * 128 * NPOS) return;
    int ij = idx % NPOS;
    int oc = (idx / NPOS) & 127;
    int b  = idx / (NPOS * 128);

    float x0 = x[(b * 3 + 0) * NPOS + ij];
    float x1 = x[(b * 3 + 1) * NPOS + ij];
    float x2 = x[(b * 3 + 2) * NPOS + ij];

    float q = bq[oc] + wq[oc*3+0]*x0 + wq[oc*3+1]*x1 + wq[oc*3+2]*x2;
    float k = bk[oc] + wk[oc*3+0]*x0 + wk[oc*3+1]*x1 + wk[oc*3+2]*x2;
    float v = bv[oc] + wv[oc*3+0]*x0 + wv[oc*3+1]*x1 + wv[oc*3+2]*x2;

    int m = oc >> 3, h = oc & 7;                    // oc = m*HEADS + h
    int dst = ((b * 8 + h) * NPOS + ij) * 16 + m;
    Q[dst] = q; K[dst] = k; V[dst] = v;
}

// ---------------- kernel 2: attention from precomputed Q/K/V ----------------
// One block per (b, ij); 8-head loop; K/V read direct from global (L2-hot).
// Softmax: max from score pass; exp fused into PV (unnormalized p, p-sum
// reduced alongside PV accumulators, single normalize at the end).
__global__ __launch_bounds__(256) void attn_ws_kernel(
    const float* __restrict__ Q, const float* __restrict__ K, const float* __restrict__ V,
    const float* __restrict__ w_out, const float* __restrict__ b_out,
    const float* __restrict__ rw1, const float* __restrict__ rb1,
    const float* __restrict__ rga, const float* __restrict__ rbe,
    const float* __restrict__ rw2, const float* __restrict__ rb2,
    const float* __restrict__ cw1, const float* __restrict__ cb1,
    const float* __restrict__ cga, const float* __restrict__ cbe,
    const float* __restrict__ cw2, const float* __restrict__ cb2,
    float* __restrict__ out)
{
    __shared__ float Er[8 * 110], Ec[8 * 110];   // transposed: [m][d]
    __shared__ float sc[4][NPOS];                // raw scores per rotation
    __shared__ float q_s[16];
    __shared__ float arow[110], acol[110];
    __shared__ float wred[4][4];
    __shared__ float Mg[4];
    __shared__ float racc[4][4][16];             // [wave][g][m]
    __shared__ float rps[4][4];                  // [wave][g]
    __shared__ float ovs[4][128];                // out_v[g][m*8+h]

    const int t    = threadIdx.x;
    const int b    = blockIdx.x / NPOS;
    const int ij   = blockIdx.x % NPOS;
    const int i    = ij / WDIM, j = ij % WDIM;
    const int lane = t & 63, wave = t >> 6;
    const float scale = 0.57735026918962576f;    // 1/sqrt(CIN=3)

    // ---- embedding-MLP tables, transposed to [m][110] ----
    {
        int d = -1;
        const float *w1 = rw1, *b1 = rb1, *ga = rga, *be = rbe, *w2 = rw2, *b2 = rb2;
        float* E = Er;
        if (t < 110) { d = t; }
        else if (t >= 128 && t < 238) { d = t - 128; w1 = cw1; b1 = cb1; ga = cga; be = cbe; w2 = cw2; b2 = cb2; E = Ec; }
        if (d >= 0) {
            float u = (d < 55) ? (-1.0f + (float)d * (2.0f / 54.0f))
                               : -(-1.0f + (float)(d - 55) * (2.0f / 54.0f));
            float hb[16], mu = 0.0f;
#pragma unroll
            for (int c = 0; c < 16; ++c) { hb[c] = u * w1[c] + b1[c]; mu += hb[c]; }
            mu *= (1.0f / 16.0f);
            float var = 0.0f;
#pragma unroll
            for (int c = 0; c < 16; ++c) { float dv = hb[c] - mu; var += dv * dv; }
            var *= (1.0f / 16.0f);
            float rstd = rsqrtf(var + 1e-5f);
#pragma unroll
            for (int c = 0; c < 16; ++c) {
                float hn = ga[c] * (hb[c] - mu) * rstd + be[c];
                hb[c] = hn / (1.0f + __expf(-hn));
            }
#pragma unroll
            for (int m = 0; m < 8; ++m) {
                float e = b2[m];
#pragma unroll
                for (int c = 0; c < 16; ++c) e += hb[c] * w2[m * 16 + c];
                E[m * 110 + d] = e;
            }
        }
    }

    for (int h = 0; h < 8; ++h) {
        const int bh = b * 8 + h;
        __syncthreads();   // tables ready (h=0); prev head's sc/ovs/racc reads done
        if (t < 16) q_s[t] = Q[(bh * NPOS + ij) * 16 + t];
        __syncthreads();

        float q[16];
#pragma unroll
        for (int m = 0; m < 16; ++m) q[m] = q_s[m];    // LDS broadcast reads

        if (t < 110) {
            float a = 0.0f;
#pragma unroll
            for (int mm = 0; mm < 8; ++mm) a += q[mm] * Er[mm * 110 + t];
            arow[t] = a;
        } else if (t >= 128 && t < 238) {
            int d = t - 128;
            float a = 0.0f;
#pragma unroll
            for (int mm = 0; mm < 8; ++mm) a += q[8 + mm] * Ec[mm * 110 + d];
            acol[d] = a;
        }
        __syncthreads();   // arow/acol ready

        // content (K direct from global) + 4-rotation scores + maxima
        float lm0 = -1e30f, lm1 = -1e30f, lm2 = -1e30f, lm3 = -1e30f;
        for (int kl = t; kl < NPOS; kl += 256) {
            const float4* kp = (const float4*)(K + (bh * NPOS + kl) * 16);
            float4 k0 = kp[0], k1 = kp[1], k2 = kp[2], k3 = kp[3];
            float c = q[0]*k0.x + q[1]*k0.y + q[2]*k0.z + q[3]*k0.w
                    + q[4]*k1.x + q[5]*k1.y + q[6]*k1.z + q[7]*k1.w
                    + q[8]*k2.x + q[9]*k2.y + q[10]*k2.z + q[11]*k2.w
                    + q[12]*k3.x + q[13]*k3.y + q[14]*k3.z + q[15]*k3.w;
            int k  = kl / WDIM, l = kl - k * WDIM;
            int a  = k - i + 27;    // rel(i,k) in [0,54]
            int c2 = l - j + 27;    // rel(j,l) in [0,54]
            float s0 = (c + arow[a]      + acol[c2]     ) * scale;
            float s1 = (c + arow[c2+55]  + acol[a]      ) * scale;
            float s2 = (c + arow[a+55]   + acol[c2+55]  ) * scale;
            float s3 = (c + arow[c2]     + acol[a+55]   ) * scale;
            sc[0][kl] = s0; sc[1][kl] = s1; sc[2][kl] = s2; sc[3][kl] = s3;
            lm0 = fmaxf(lm0, s0); lm1 = fmaxf(lm1, s1);
            lm2 = fmaxf(lm2, s2); lm3 = fmaxf(lm3, s3);
        }
        lm0 = wave_max64(lm0); lm1 = wave_max64(lm1);
        lm2 = wave_max64(lm2); lm3 = wave_max64(lm3);
        if (lane == 0) { wred[0][wave]=lm0; wred[1][wave]=lm1; wred[2][wave]=lm2; wred[3][wave]=lm3; }
        __syncthreads();
        if (t < 4) Mg[t] = fmaxf(fmaxf(wred[t][0], wred[t][1]), fmaxf(wred[t][2], wred[t][3]));
        __syncthreads();
        const float M0 = Mg[0], M1 = Mg[1], M2 = Mg[2], M3 = Mg[3];

        // PV with fused exp: thread = (m4 = t&3 float4-of-m, ch = t>>2).
        // kl = s*64 + ch: V loads fully coalesced (1 KB/wave-instr).
        {
            int m4 = t & 3, ch = t >> 2;
            float4 a0 = {0,0,0,0}, a1 = {0,0,0,0}, a2 = {0,0,0,0}, a3 = {0,0,0,0};
            float p0s = 0.0f, p1s = 0.0f, p2s = 0.0f, p3s = 0.0f;
#pragma unroll
            for (int s = 0; s < 13; ++s) {
                int kl = s * 64 + ch;
                if (kl < NPOS) {
                    float4 vv = ((const float4*)(V + (bh * NPOS + kl) * 16))[m4];
                    float p0 = __expf(sc[0][kl] - M0);
                    float p1 = __expf(sc[1][kl] - M1);
                    float p2 = __expf(sc[2][kl] - M2);
                    float p3 = __expf(sc[3][kl] - M3);
                    p0s += p0; p1s += p1; p2s += p2; p3s += p3;
                    a0.x += p0*vv.x; a0.y += p0*vv.y; a0.z += p0*vv.z; a0.w += p0*vv.w;
                    a1.x += p1*vv.x; a1.y += p1*vv.y; a1.z += p1*vv.z; a1.w += p1*vv.w;
                    a2.x += p2*vv.x; a2.y += p2*vv.y; a2.z += p2*vv.z; a2.w += p2*vv.w;
                    a3.x += p3*vv.x; a3.y += p3*vv.y; a3.z += p3*vv.z; a3.w += p3*vv.w;
                }
            }
            // reduce over ch within wave (stride-4 lane groups share m4)
#pragma unroll
            for (int off = 4; off < 64; off <<= 1) {
                a0.x += __shfl_down(a0.x, off, 64); a0.y += __shfl_down(a0.y, off, 64);
                a0.z += __shfl_down(a0.z, off, 64); a0.w += __shfl_down(a0.w, off, 64);
                a1.x += __shfl_down(a1.x, off, 64); a1.y += __shfl_down(a1.y, off, 64);
                a1.z += __shfl_down(a1.z, off, 64); a1.w += __shfl_down(a1.w, off, 64);
                a2.x += __shfl_down(a2.x, off, 64); a2.y += __shfl_down(a2.y, off, 64);
                a2.z += __shfl_down(a2.z, off, 64); a2.w += __shfl_down(a2.w, off, 64);
                a3.x += __shfl_down(a3.x, off, 64); a3.y += __shfl_down(a3.y, off, 64);
                a3.z += __shfl_down(a3.z, off, 64); a3.w += __shfl_down(a3.w, off, 64);
                p0s  += __shfl_down(p0s,  off, 64);
                p1s  += __shfl_down(p1s,  off, 64);
                p2s  += __shfl_down(p2s,  off, 64);
                p3s  += __shfl_down(p3s,  off, 64);
            }
            if (lane < 4) {
                ((float4*)&racc[wave][0][lane * 4])[0] = a0;
                ((float4*)&racc[wave][1][lane * 4])[0] = a1;
                ((float4*)&racc[wave][2][lane * 4])[0] = a2;
                ((float4*)&racc[wave][3][lane * 4])[0] = a3;
                if (lane == 0) { rps[wave][0]=p0s; rps[wave][1]=p1s; rps[wave][2]=p2s; rps[wave][3]=p3s; }
            }
        }
        __syncthreads();
        if (t < 64) {
            int g = t >> 4, m = t & 15;
            float sum = racc[0][g][m] + racc[1][g][m] + racc[2][g][m] + racc[3][g][m];
            float ps  = rps[0][g] + rps[1][g] + rps[2][g] + rps[3][g];
            ovs[g][m * 8 + h] = sum / ps;
        }
    }
    __syncthreads();

    // output projection: wave = g (LDS broadcast), o = lane; out (B,64,G,28,28)
    {
        int g = wave, o = lane;
        float acc = b_out[o];
        const float* wr = w_out + o * 128;
        const float* ov = ovs[g];
#pragma unroll 8
        for (int c = 0; c < 128; ++c) acc += wr[c] * ov[c];
        out[((b * 64 + o) * 4 + g) * NPOS + ij] = acc;
    }
}

// ---------------- fallback (round-4 proven kernel, no ws) ----------------
__global__ __launch_bounds__(256) void attn_all_kernel(
    const float* __restrict__ x,
    const float* __restrict__ wq, const float* __restrict__ bq,
    const float* __restrict__ wk, const float* __restrict__ bk,
    const float* __restrict__ wv, const float* __restrict__ bv,
    const float* __restrict__ w_out, const float* __restrict__ b_out,
    const float* __restrict__ rw1, const float* __restrict__ rb1,
    const float* __restrict__ rga, const float* __restrict__ rbe,
    const float* __restrict__ rw2, const float* __restrict__ rb2,
    const float* __restrict__ cw1, const float* __restrict__ cb1,
    const float* __restrict__ cga, const float* __restrict__ cbe,
    const float* __restrict__ cw2, const float* __restrict__ cb2,
    float* __restrict__ out)
{
    __shared__ float Er[110 * 8], Ec[110 * 8];
    __shared__ float KV[16 * NPOS];
    __shared__ float sc[4][NPOS];
    __shared__ float arow[110], acol[110];
    __shared__ float wred[4][4];
    __shared__ float Mg[4], invs[4];
    __shared__ float ovs[4][128];

    const int t    = threadIdx.x;
    const int b    = blockIdx.x / NPOS;
    const int ij   = blockIdx.x % NPOS;
    const int i    = ij / WDIM, j = ij % WDIM;
    const int lane = t & 63, wave = t >> 6;
    const float scale = 0.57735026918962576f;

    {
        int d = -1;
        const float *w1 = rw1, *b1 = rb1, *ga = rga, *be = rbe, *w2 = rw2, *b2 = rb2;
        float* E = Er;
        if (t < 110) { d = t; }
        else if (t >= 128 && t < 238) { d = t - 128; w1 = cw1; b1 = cb1; ga = cga; be = cbe; w2 = cw2; b2 = cb2; E = Ec; }
        if (d >= 0) {
            float u = (d < 55) ? (-1.0f + (float)d * (2.0f / 54.0f))
                               : -(-1.0f + (float)(d - 55) * (2.0f / 54.0f));
            float hb[16], mu = 0.0f;
#pragma unroll
            for (int c = 0; c < 16; ++c) { hb[c] = u * w1[c] + b1[c]; mu += hb[c]; }
            mu *= (1.0f / 16.0f);
            float var = 0.0f;
#pragma unroll
            for (int c = 0; c < 16; ++c) { float dv = hb[c] - mu; var += dv * dv; }
            var *= (1.0f / 16.0f);
            float rstd = rsqrtf(var + 1e-5f);
#pragma unroll
            for (int c = 0; c < 16; ++c) {
                float hn = ga[c] * (hb[c] - mu) * rstd + be[c];
                hb[c] = hn / (1.0f + __expf(-hn));
            }
#pragma unroll
            for (int m = 0; m < 8; ++m) {
                float e = b2[m];
#pragma unroll
                for (int c = 0; c < 16; ++c) e += hb[c] * w2[m * 16 + c];
                E[d * 8 + m] = e;
            }
        }
    }

    const float xq0 = x[(b * 3 + 0) * NPOS + ij];
    const float xq1 = x[(b * 3 + 1) * NPOS + ij];
    const float xq2 = x[(b * 3 + 2) * NPOS + ij];

    for (int h = 0; h < 8; ++h) {
        __syncthreads();
        float q[16];
#pragma unroll
        for (int m = 0; m < 16; ++m) {
            int oc = m * 8 + h;
            q[m] = bq[oc] + wq[oc*3+0]*xq0 + wq[oc*3+1]*xq1 + wq[oc*3+2]*xq2;
        }
        for (int kl = t; kl < NPOS; kl += 256) {
            float x0 = x[(b * 3 + 0) * NPOS + kl];
            float x1 = x[(b * 3 + 1) * NPOS + kl];
            float x2 = x[(b * 3 + 2) * NPOS + kl];
#pragma unroll
            for (int m = 0; m < 16; ++m) {
                int oc = m * 8 + h;
                KV[m * NPOS + kl] = bk[oc] + wk[oc*3+0]*x0 + wk[oc*3+1]*x1 + wk[oc*3+2]*x2;
            }
        }
        if (t < 110) {
            float a = 0.0f;
#pragma unroll
            for (int mm = 0; mm < 8; ++mm) a += q[mm] * Er[t * 8 + mm];
            arow[t] = a;
        } else if (t >= 128 && t < 238) {
            int d = t - 128;
            float a = 0.0f;
#pragma unroll
            for (int mm = 0; mm < 8; ++mm) a += q[8 + mm] * Ec[d * 8 + mm];
            acol[d] = a;
        }
        __syncthreads();

        float lm0 = -1e30f, lm1 = -1e30f, lm2 = -1e30f, lm3 = -1e30f;
        for (int kl = t; kl < NPOS; kl += 256) {
            float c = 0.0f;
#pragma unroll
            for (int m = 0; m < 16; ++m) c += q[m] * KV[m * NPOS + kl];
            int k  = kl / WDIM, l = kl - k * WDIM;
            int a  = k - i + 27;
            int c2 = l - j + 27;
            float s0 = (c + arow[a]      + acol[c2]     ) * scale;
            float s1 = (c + arow[c2+55]  + acol[a]      ) * scale;
            float s2 = (c + arow[a+55]   + acol[c2+55]  ) * scale;
            float s3 = (c + arow[c2]     + acol[a+55]   ) * scale;
            sc[0][kl] = s0; sc[1][kl] = s1; sc[2][kl] = s2; sc[3][kl] = s3;
            lm0 = fmaxf(lm0, s0); lm1 = fmaxf(lm1, s1);
            lm2 = fmaxf(lm2, s2); lm3 = fmaxf(lm3, s3);
        }
        lm0 = wave_max64(lm0); lm1 = wave_max64(lm1);
        lm2 = wave_max64(lm2); lm3 = wave_max64(lm3);
        if (lane == 0) { wred[0][wave]=lm0; wred[1][wave]=lm1; wred[2][wave]=lm2; wred[3][wave]=lm3; }
        __syncthreads();
        if (t < 4) Mg[t] = fmaxf(fmaxf(wred[t][0], wred[t][1]), fmaxf(wred[t][2], wred[t][3]));
        __syncthreads();
        float M0 = Mg[0], M1 = Mg[1], M2 = Mg[2], M3 = Mg[3];

        for (int kl = t; kl < NPOS; kl += 256) {
            float x0 = x[(b * 3 + 0) * NPOS + kl];
            float x1 = x[(b * 3 + 1) * NPOS + kl];
            float x2 = x[(b * 3 + 2) * NPOS + kl];
#pragma unroll
            for (int m = 0; m < 16; ++m) {
                int oc = m * 8 + h;
                KV[m * NPOS + kl] = bv[oc] + wv[oc*3+0]*x0 + wv[oc*3+1]*x1 + wv[oc*3+2]*x2;
            }
        }

        float ls0 = 0.0f, ls1 = 0.0f, ls2 = 0.0f, ls3 = 0.0f;
        for (int kl = t; kl < NPOS; kl += 256) {
            float p0 = __expf(sc[0][kl] - M0); sc[0][kl] = p0; ls0 += p0;
            float p1 = __expf(sc[1][kl] - M1); sc[1][kl] = p1; ls1 += p1;
            float p2 = __expf(sc[2][kl] - M2); sc[2][kl] = p2; ls2 += p2;
            float p3 = __expf(sc[3][kl] - M3); sc[3][kl] = p3; ls3 += p3;
        }
        ls0 = wave_sum64(ls0); ls1 = wave_sum64(ls1);
        ls2 = wave_sum64(ls2); ls3 = wave_sum64(ls3);
        if (lane == 0) { wred[0][wave]=ls0; wred[1][wave]=ls1; wred[2][wave]=ls2; wred[3][wave]=ls3; }
        __syncthreads();
        if (t < 4) invs[t] = 1.0f / (wred[t][0] + wred[t][1] + wred[t][2] + wred[t][3]);
        __syncthreads();

        {
            int m = t >> 4, ch = t & 15;
            float a0 = 0.0f, a1 = 0.0f, a2 = 0.0f, a3 = 0.0f;
            int base = ch * 49;
            for (int s = 0; s < 49; ++s) {
                int kl = base + s;
                float vv = KV[m * NPOS + kl];
                a0 += sc[0][kl] * vv; a1 += sc[1][kl] * vv;
                a2 += sc[2][kl] * vv; a3 += sc[3][kl] * vv;
            }
#pragma unroll
            for (int off = 8; off > 0; off >>= 1) {
                a0 += __shfl_down(a0, off, 16); a1 += __shfl_down(a1, off, 16);
                a2 += __shfl_down(a2, off, 16); a3 += __shfl_down(a3, off, 16);
            }
            if (ch == 0) {
                ovs[0][m * 8 + h] = a0 * invs[0];
                ovs[1][m * 8 + h] = a1 * invs[1];
                ovs[2][m * 8 + h] = a2 * invs[2];
                ovs[3][m * 8 + h] = a3 * invs[3];
            }
        }
    }
    __syncthreads();
    {
        int o = t >> 2, g = t & 3;
        float acc = b_out[o];
        const float* wr = w_out + o * 128;
        const float* ov = ovs[g];
#pragma unroll 8
        for (int c = 0; c < 128; ++c) acc += wr[c] * ov[c];
        out[((b * 64 + o) * 4 + g) * NPOS + ij] = acc;
    }
}

extern "C" void kernel_launch(void* const* d_in, const int* in_sizes, int n_in,
                              void* d_out, int out_size, void* d_ws, size_t ws_size,
                              hipStream_t stream)
{
    const float* x     = (const float*)d_in[0];
    const float* wq    = (const float*)d_in[1];
    const float* bq    = (const float*)d_in[2];
    const float* wk    = (const float*)d_in[3];
    const float* bk    = (const float*)d_in[4];
    const float* wv    = (const float*)d_in[5];
    const float* bv    = (const float*)d_in[6];
    const float* w_out = (const float*)d_in[7];
    const float* b_out = (const float*)d_in[8];
    const float* rw1 = (const float*)d_in[9];
    const float* rb1 = (const float*)d_in[10];
    const float* rga = (const float*)d_in[11];
    const float* rbe = (const float*)d_in[12];
    const float* rw2 = (const float*)d_in[13];
    const float* rb2 = (const float*)d_in[14];
    const float* cw1 = (const float*)d_in[15];
    const float* cb1 = (const float*)d_in[16];
    const float* cga = (const float*)d_in[17];
    const float* cbe = (const float*)d_in[18];
    const float* cw2 = (const float*)d_in[19];
    const float* cb2 = (const float*)d_in[20];
    // d_in[21]/d_in[22] (ridx/cidx) unused: closed-form rotation indices.

    const size_t need = (size_t)3 * 401408 * sizeof(float);   // Q+K+V = 4.8 MB
    if (ws_size >= need) {
        float* Q = (float*)d_ws;
        float* K = Q + 401408;
        float* V = K + 401408;
        qkv_kernel<<<1568, 256, 0, stream>>>(x, wq, bq, wk, bk, wv, bv, Q, K, V);
        attn_ws_kernel<<<4 * NPOS, 256, 0, stream>>>(
            Q, K, V, w_out, b_out,
            rw1, rb1, rga, rbe, rw2, rb2,
            cw1, cb1, cga, cbe, cw2, cb2,
            (float*)d_out);
    } else {
        attn_all_kernel<<<4 * NPOS, 256, 0, stream>>>(
            x, wq, bq, wk, bk, wv, bv, w_out, b_out,
            rw1, rb1, rga, rbe, rw2, rb2,
            cw1, cb1, cga, cbe, cw2, cb2,
            (float*)d_out);
    }
}